// Round 4
// baseline (414.792 us; speedup 1.0000x reference)
//
#include <hip/hip_runtime.h>

#define N_EDGES 160000
#define C_EMB 32
#define N_RBF 32

typedef float floatx4 __attribute__((ext_vector_type(4)));

#define PI_F 3.14159265358979323f

// ============================ K1: compact features ============================
// Per edge -> ws_c[96] (env & hz folded in), ws_basis[28] (27 basis + env).
#define EPB1 32
#define T1 256

__global__ __launch_bounds__(T1) void k1_features(
    const int* __restrict__ atomic_numbers,
    const int* __restrict__ nbr,
    const float* __restrict__ ev,
    const float* __restrict__ z_table,
    const float* __restrict__ z_map_W,
    const float* __restrict__ dense_W,
    const float* __restrict__ dense_b,
    const float* __restrict__ rbf_beta,
    const float* __restrict__ rbf_centres,
    float* __restrict__ ws_c,       // (N_EDGES, 96)
    float* __restrict__ ws_basis)   // (N_EDGES, 28)
{
    __shared__ float s_hi[EPB1][C_EMB];
    __shared__ float s_hj[EPB1][C_EMB];
    __shared__ float s_rbf[EPB1][N_RBF];
    __shared__ float s_hz[EPB1][C_EMB];
    __shared__ float s_env[EPB1];

    const int tid = threadIdx.x;
    const int e0 = blockIdx.x * EPB1;

    // gather atom embeddings
    for (int idx = tid; idx < EPB1 * C_EMB; idx += T1) {
        int e = idx >> 5, k = idx & 31, ge = e0 + e;
        s_hi[e][k] = z_table[atomic_numbers[nbr[ge]] * C_EMB + k];
        s_hj[e][k] = z_table[atomic_numbers[nbr[N_EDGES + ge]] * C_EMB + k];
    }
    // rbf + env
    for (int idx = tid; idx < EPB1 * N_RBF; idx += T1) {
        int e = idx >> 5, n = idx & 31, ge = e0 + e;
        float x = ev[ge * 3 + 0], y = ev[ge * 3 + 1], z = ev[ge * 3 + 2];
        float r = sqrtf(x * x + y * y + z * z);
        float d = __expf(-r) - rbf_centres[n];
        s_rbf[e][n] = __expf(-rbf_beta[n] * d * d);
        if (n == 0) {
            float env = (r < 5.0f) ? 0.5f * (__cosf(PI_F * r * 0.2f) + 1.0f) : 0.0f;
            s_env[e] = env;
            ws_basis[ge * 28 + 27] = env;
        }
    }
    // geometric basis -> ws
    for (int idx = tid; idx < EPB1 * 27; idx += T1) {
        int e = idx / 27, t = idx - e * 27, ge = e0 + e;
        float x = ev[ge * 3 + 0], y = ev[ge * 3 + 1], z = ev[ge * 3 + 2];
        float rinv = rsqrtf(x * x + y * y + z * z);
        float vx = x * rinv, vy = y * rinv, vz = z * rinv;
        float val;
        if (t < 9) {
            val = (t == 0 || t == 4 || t == 8) ? 1.0f : 0.0f;
        } else if (t < 18) {
            int p = t - 9;
            switch (p) {
                case 1: val = -vz; break;
                case 2: val =  vy; break;
                case 3: val =  vz; break;
                case 5: val = -vx; break;
                case 6: val = -vy; break;
                case 7: val =  vx; break;
                default: val = 0.0f; break;
            }
        } else {
            int p = t - 18;
            int i = p / 3, j = p - 3 * i;
            float ri = (i == 0) ? vx : ((i == 1) ? vy : vz);
            float rj = (j == 0) ? vx : ((j == 1) ? vy : vz);
            val = ri * rj - ((i == j) ? (1.0f / 3.0f) : 0.0f);
        }
        ws_basis[ge * 28 + t] = val;
    }
    __syncthreads();

    // h_z
    for (int idx = tid; idx < EPB1 * C_EMB; idx += T1) {
        int e = idx >> 5, cc = idx & 31;
        const float4* Wi  = (const float4*)(z_map_W + cc * 64);
        const float4* hi4 = (const float4*)s_hi[e];
        const float4* hj4 = (const float4*)s_hj[e];
        float acc = 0.0f;
        #pragma unroll
        for (int k = 0; k < 8; ++k) {
            float4 w = Wi[k]; float4 h = hi4[k];
            acc += w.x * h.x + w.y * h.y + w.z * h.z + w.w * h.w;
        }
        #pragma unroll
        for (int k = 0; k < 8; ++k) {
            float4 w = Wi[8 + k]; float4 h = hj4[k];
            acc += w.x * h.x + w.y * h.y + w.z * h.z + w.w * h.w;
        }
        s_hz[e][cc] = acc;
    }
    __syncthreads();

    // c = (b + rbf.W) * env * hz  -> ws (coalesced: consecutive m)
    for (int idx = tid; idx < EPB1 * 96; idx += T1) {
        int e = idx / 96, m = idx - e * 96, ge = e0 + e;
        int cc = m & 31;
        const float4* Wd  = (const float4*)(dense_W + m * 32);
        const float4* rb4 = (const float4*)s_rbf[e];
        float acc = dense_b[m];
        #pragma unroll
        for (int n = 0; n < 8; ++n) {
            float4 w = Wd[n]; float4 rv = rb4[n];
            acc += w.x * rv.x + w.y * rv.y + w.z * rv.z + w.w * rv.w;
        }
        ws_c[(size_t)ge * 96 + m] = acc * s_env[e] * s_hz[e][cc];
    }
}

// ============================ K2: streaming expansion =========================
// One block = one region (I/A/S) x 32 edges. Stage 4.6 KB -> LDS, then pure
// float4 store stream (9 per thread), regular (cached) stores.
#define EPB2 32
#define T2 256
#define EBLK (N_EDGES / EPB2)   // 5000

__global__ __launch_bounds__(T2) void k2_expand(
    const float* __restrict__ ws_c,
    const float* __restrict__ ws_basis,
    float* __restrict__ out)
{
    __shared__ float s_cc[EPB2][C_EMB];
    __shared__ float s_bb[EPB2][12];

    const int tid = threadIdx.x;
    const int bid = blockIdx.x;
    const int r   = bid / EBLK;        // region 0,1,2
    const int eb  = bid - r * EBLK;
    const int e0  = eb * EPB2;

    for (int idx = tid; idx < EPB2 * C_EMB; idx += T2) {
        int e = idx >> 5, cc = idx & 31;
        s_cc[e][cc] = ws_c[(size_t)(e0 + e) * 96 + r * 32 + cc];
    }
    for (int idx = tid; idx < EPB2 * 9; idx += T2) {
        int e = idx / 9, p = idx - e * 9;
        s_bb[e][p] = ws_basis[(e0 + e) * 28 + 9 * r + p];
    }
    __syncthreads();

    float* ob = out + (size_t)r * N_EDGES * 288 + (size_t)e0 * 288;
    const int NQ = EPB2 * 288 / 4;     // 2304
    #pragma unroll 3
    for (int q = tid; q < NQ; q += T2) {
        int f = q * 4;
        floatx4 v;
        #pragma unroll
        for (int u = 0; u < 4; ++u) {
            int ff = f + u;
            int e = ff / 288;
            int rem = ff - e * 288;
            int cc = rem / 9;
            int p = rem - cc * 9;
            v[u] = s_cc[e][cc] * s_bb[e][p];
        }
        ((floatx4*)ob)[q] = v;
    }
}

// ===================== Fallback: proven R1 single kernel ======================
#define EPBF 16
#define TF 256

__global__ __launch_bounds__(TF) void edge_embed_fallback(
    const int* __restrict__ atomic_numbers,
    const int* __restrict__ nbr,
    const float* __restrict__ ev,
    const float* __restrict__ z_table,
    const float* __restrict__ z_map_W,
    const float* __restrict__ dense_W,
    const float* __restrict__ dense_b,
    const float* __restrict__ rbf_beta,
    const float* __restrict__ rbf_centres,
    float* __restrict__ out)
{
    __shared__ float s_hi[EPBF][C_EMB];
    __shared__ float s_hj[EPBF][C_EMB];
    __shared__ float s_rbf[EPBF][N_RBF];
    __shared__ float s_hz[EPBF][C_EMB];
    __shared__ float s_c[EPBF][96];
    __shared__ float s_basis[EPBF][28];

    const int tid = threadIdx.x;
    const int e0 = blockIdx.x * EPBF;

    for (int idx = tid; idx < EPBF * C_EMB; idx += TF) {
        int e = idx >> 5, k = idx & 31, ge = e0 + e;
        s_hi[e][k] = z_table[atomic_numbers[nbr[ge]] * C_EMB + k];
        s_hj[e][k] = z_table[atomic_numbers[nbr[N_EDGES + ge]] * C_EMB + k];
    }
    for (int idx = tid; idx < EPBF * N_RBF; idx += TF) {
        int e = idx >> 5, n = idx & 31, ge = e0 + e;
        float x = ev[ge * 3 + 0], y = ev[ge * 3 + 1], z = ev[ge * 3 + 2];
        float r = sqrtf(x * x + y * y + z * z);
        float d = __expf(-r) - rbf_centres[n];
        s_rbf[e][n] = __expf(-rbf_beta[n] * d * d);
        if (n == 0)
            s_basis[e][27] = (r < 5.0f) ? 0.5f * (__cosf(PI_F * r * 0.2f) + 1.0f) : 0.0f;
    }
    for (int idx = tid; idx < EPBF * 27; idx += TF) {
        int e = idx / 27, t = idx - e * 27, ge = e0 + e;
        float x = ev[ge * 3 + 0], y = ev[ge * 3 + 1], z = ev[ge * 3 + 2];
        float rinv = rsqrtf(x * x + y * y + z * z);
        float vx = x * rinv, vy = y * rinv, vz = z * rinv;
        float val;
        if (t < 9) val = (t == 0 || t == 4 || t == 8) ? 1.0f : 0.0f;
        else if (t < 18) {
            int p = t - 9;
            switch (p) {
                case 1: val = -vz; break;
                case 2: val =  vy; break;
                case 3: val =  vz; break;
                case 5: val = -vx; break;
                case 6: val = -vy; break;
                case 7: val =  vx; break;
                default: val = 0.0f; break;
            }
        } else {
            int p = t - 18;
            int i = p / 3, j = p - 3 * i;
            float ri = (i == 0) ? vx : ((i == 1) ? vy : vz);
            float rj = (j == 0) ? vx : ((j == 1) ? vy : vz);
            val = ri * rj - ((i == j) ? (1.0f / 3.0f) : 0.0f);
        }
        s_basis[e][t] = val;
    }
    __syncthreads();
    for (int idx = tid; idx < EPBF * C_EMB; idx += TF) {
        int e = idx >> 5, cc = idx & 31;
        const float4* Wi  = (const float4*)(z_map_W + cc * 64);
        const float4* hi4 = (const float4*)s_hi[e];
        const float4* hj4 = (const float4*)s_hj[e];
        float acc = 0.0f;
        #pragma unroll
        for (int k = 0; k < 8; ++k) {
            float4 w = Wi[k]; float4 h = hi4[k];
            acc += w.x * h.x + w.y * h.y + w.z * h.z + w.w * h.w;
        }
        #pragma unroll
        for (int k = 0; k < 8; ++k) {
            float4 w = Wi[8 + k]; float4 h = hj4[k];
            acc += w.x * h.x + w.y * h.y + w.z * h.z + w.w * h.w;
        }
        s_hz[e][cc] = acc;
    }
    __syncthreads();
    for (int idx = tid; idx < EPBF * 96; idx += TF) {
        int e = idx / 96, m = idx - e * 96;
        int cc = m & 31;
        const float4* Wd  = (const float4*)(dense_W + m * 32);
        const float4* rb4 = (const float4*)s_rbf[e];
        float acc = dense_b[m];
        #pragma unroll
        for (int n = 0; n < 8; ++n) {
            float4 w = Wd[n]; float4 rv = rb4[n];
            acc += w.x * rv.x + w.y * rv.y + w.z * rv.z + w.w * rv.w;
        }
        s_c[e][m] = acc * s_basis[e][27] * s_hz[e][cc];
    }
    __syncthreads();
    float* outI = out + (size_t)e0 * 288;
    float* outA = out + (size_t)N_EDGES * 288 + (size_t)e0 * 288;
    float* outS = out + (size_t)N_EDGES * 576 + (size_t)e0 * 288;
    const int NQ = EPBF * 288 / 4;
    for (int q = tid; q < NQ; q += TF) {
        int fbase = q * 4;
        floatx4 aI, aA, aS;
        #pragma unroll
        for (int u = 0; u < 4; ++u) {
            int f = fbase + u;
            int e = f / 288;
            int rem = f - e * 288;
            int cc = rem / 9;
            int p = rem - cc * 9;
            aI[u] = s_c[e][cc]      * s_basis[e][p];
            aA[u] = s_c[e][32 + cc] * s_basis[e][9 + p];
            aS[u] = s_c[e][64 + cc] * s_basis[e][18 + p];
        }
        ((floatx4*)outI)[q] = aI;
        ((floatx4*)outA)[q] = aA;
        ((floatx4*)outS)[q] = aS;
    }
}

extern "C" void kernel_launch(void* const* d_in, const int* in_sizes, int n_in,
                              void* d_out, int out_size, void* d_ws, size_t ws_size,
                              hipStream_t stream) {
    const int*   an  = (const int*)d_in[0];
    const int*   nbr = (const int*)d_in[1];
    const float* ev  = (const float*)d_in[2];
    const float* zt  = (const float*)d_in[3];
    const float* zw  = (const float*)d_in[4];
    const float* dw  = (const float*)d_in[5];
    const float* db  = (const float*)d_in[6];
    const float* rb  = (const float*)d_in[7];
    const float* rc  = (const float*)d_in[8];
    float* outp = (float*)d_out;

    const size_t need_c = (size_t)N_EDGES * 96 * sizeof(float);   // 61.44 MB
    const size_t need_b = (size_t)N_EDGES * 28 * sizeof(float);   // 17.92 MB

    if (ws_size >= need_c + need_b) {
        float* ws_c     = (float*)d_ws;
        float* ws_basis = (float*)((char*)d_ws + need_c);
        k1_features<<<dim3(N_EDGES / EPB1), T1, 0, stream>>>(
            an, nbr, ev, zt, zw, dw, db, rb, rc, ws_c, ws_basis);
        k2_expand<<<dim3(3 * EBLK), T2, 0, stream>>>(ws_c, ws_basis, outp);
    } else {
        edge_embed_fallback<<<dim3(N_EDGES / EPBF), TF, 0, stream>>>(
            an, nbr, ev, zt, zw, dw, db, rb, rc, outp);
    }
}